// Round 7
// baseline (340.352 us; speedup 1.0000x reference)
//
#include <hip/hip_runtime.h>
#include <math.h>

#define NN 500000
#define CH 128
#define NG 1024
#define GRID 256
#define TILES ((NN + 127) >> 7)   // 3907 tiles of 128 rows

typedef __attribute__((ext_vector_type(8))) short short8v;
typedef __attribute__((ext_vector_type(4))) float f32x4;

__device__ __forceinline__ void bf16_split(float f, unsigned short& h, unsigned short& l){
  const unsigned u = __float_as_uint(f);
  h = (unsigned short)(u >> 16);
  const float hif = __uint_as_float(u & 0xffff0000u);
  const float lof = f - hif;
  l = (unsigned short)(__float_as_uint(lof) >> 16);
}

__device__ __forceinline__ void gld_lds16(const void* g, void* l){
  __builtin_amdgcn_global_load_lds(
      (__attribute__((address_space(1))) void*)g,
      (__attribute__((address_space(3))) void*)l, 16, 0, 0);
}

// Prep: (a) t<2048: transpose + bf16-hi/lo-split W1 into Wg (pre-swizzled:
// byte = (n*256 + k*2) ^ ((n&7)<<4); hi at 0, lo at +32KB).
// (b) zero out[NG*CH] and den[NG].
__global__ __launch_bounds__(256) void prep_kernel(
    const float* __restrict__ W1, unsigned short* __restrict__ Wg,
    float* __restrict__ out, float* __restrict__ den){
  const int t = blockIdx.x * 256 + threadIdx.x;
  if (t < 2048){
    const int n  = t >> 4;
    const int k0 = (t & 15) << 3;
    unsigned short hv[8], lv[8];
    #pragma unroll
    for (int i = 0; i < 8; i++)
      bf16_split(W1[(size_t)(k0 + i) * CH + n], hv[i], lv[i]);
    const int byte = (n * 256 + k0 * 2) ^ ((n & 7) << 4);
    *reinterpret_cast<short8v*>(reinterpret_cast<char*>(Wg) + byte) =
        *reinterpret_cast<short8v*>(hv);
    *reinterpret_cast<short8v*>(reinterpret_cast<char*>(Wg) + 32768 + byte) =
        *reinterpret_cast<short8v*>(lv);
  }
  const float4 z = make_float4(0.f, 0.f, 0.f, 0.f);
  float4* out4 = reinterpret_cast<float4*>(out);
  float4* den4 = reinterpret_cast<float4*>(den);
  const int nthr = gridDim.x * 256;
  for (int i = t; i < 32768 + 256; i += nthr){
    if (i < 32768) out4[i] = z;
    else den4[i - 32768] = z;
  }
}

// Fused scores+softmax+pool. 256 thr, 128-row tiles, 4x16KB K-slice slots,
// prefetch depth 3, counted vmcnt(8) per phase (never drain-0 in loop).
// Pooling reads x from global (L2-hot), es/bs via LDS.
__global__ __launch_bounds__(256, 2) void fused_kernel(
    const float* __restrict__ x, const int* __restrict__ batch,
    const unsigned short* __restrict__ Wg,
    const float* __restrict__ b1, const float* __restrict__ w2,
    const float* __restrict__ b2,
    float* __restrict__ out, float* __restrict__ den)
{
  __shared__ unsigned short WB[2 * CH * CH];   // 64KB W^T hi|lo, swizzled
  __shared__ char XS[4 * 16384];               // 4 slots: 128 rows x 32 k fp32
  __shared__ float es[128];
  __shared__ int   bsg[128];

  const int tid = threadIdx.x;
  const int w   = tid >> 6;
  const int l   = tid & 63;
  const int l15 = l & 15;
  const int g   = l >> 4;       // 0..3
  const int x7  = l15 & 7;

  const int bid = blockIdx.x;
  const int ntb = (TILES - 1 - bid) / GRID + 1;
  const int NP  = ntb * 4;
  const bool is64 = (batch[NN - 1] == 0);   // int64-vs-int32 runtime hedge
  const float b2v = b2[0];

  float b1r[8], w2r[8];
  #pragma unroll
  for (int ct = 0; ct < 8; ct++){
    b1r[ct] = b1[ct * 16 + l15];
    w2r[ct] = w2[ct * 16 + l15];
  }

  // Stage W (pre-split, coalesced, conflict-free), once.
  {
    const short8v* __restrict__ src = reinterpret_cast<const short8v*>(Wg);
    short8v* dst = reinterpret_cast<short8v*>(WB);
    #pragma unroll
    for (int it = 0; it < 16; ++it)
      dst[it * 256 + tid] = src[it * 256 + tid];
  }

  // Stage K-slice phase P (tile = bid + (P>>2)*GRID, ks = P&3) into slot P&3.
  // LDS[R][c] = src[R][c ^ (R&7)] (linear dest, pre-swizzled source).
  auto stage = [&](int P){
    char* base = XS + (P & 3) * 16384;
    const int u  = bid + (P >> 2) * GRID;
    const int ks = P & 3;
    #pragma unroll
    for (int p = 0; p < 4; ++p){
      const int idx = p * 256 + tid;     // 16B chunk id 0..1023
      const int R = idx >> 3, c = idx & 7;
      int row = u * 128 + R;
      row = row < NN ? row : NN - 1;     // clamp; es=0 masks contribution
      const char* gsrc = (const char*)x + (size_t)row * 512 + ks * 128 + ((c ^ (R & 7)) << 4);
      gld_lds16(gsrc, base + idx * 16);
    }
  };

  stage(0); stage(1); stage(2);
  __syncthreads();   // one-time drain: W, prefetches visible

  for (int ti = 0; ti < ntb; ++ti){
    const int u = bid + ti * GRID;
    const int tilebase = u * 128;

    f32x4 acc[2][8];
    #pragma unroll
    for (int a = 0; a < 2; a++)
      #pragma unroll
      for (int b = 0; b < 8; b++) acc[a][b] = (f32x4)0.f;

    #pragma unroll
    for (int ks = 0; ks < 4; ++ks){
      const int P = ti * 4 + ks;
      asm volatile("s_waitcnt vmcnt(8)" ::: "memory");
      __builtin_amdgcn_s_barrier();
      __builtin_amdgcn_sched_barrier(0);
      if (P + 3 < NP) stage(P + 3);

      const char* sb = XS + ks * 16384;  // slot == ks (4 phases/tile)

      // A fragments: lane l -> x[R = w*32+nt*16+l15][k = ks*32 + g*8 + j]
      short8v Ah[2], Al[2];
      #pragma unroll
      for (int nt = 0; nt < 2; ++nt){
        const char* bp = sb + (w * 32 + nt * 16 + l15) * 128;
        float fv[8];
        *reinterpret_cast<float4*>(fv) =
            *reinterpret_cast<const float4*>(bp + (((2 * g)     ^ x7) << 4));
        *reinterpret_cast<float4*>(fv + 4) =
            *reinterpret_cast<const float4*>(bp + (((2 * g + 1) ^ x7) << 4));
        unsigned short hv[8], lv[8];
        #pragma unroll
        for (int j = 0; j < 8; j++) bf16_split(fv[j], hv[j], lv[j]);
        Ah[nt] = *reinterpret_cast<short8v*>(hv);
        Al[nt] = *reinterpret_cast<short8v*>(lv);
      }

      #pragma unroll
      for (int ct = 0; ct < 8; ++ct){
        const int n = ct * 16 + l15;
        const int byte = (n * 256 + ks * 64 + g * 16) ^ ((n & 7) << 4);
        const short8v Bh = *reinterpret_cast<const short8v*>((const char*)WB + byte);
        const short8v Bl = *reinterpret_cast<const short8v*>((const char*)WB + 32768 + byte);
        #pragma unroll
        for (int nt = 0; nt < 2; ++nt){
          acc[nt][ct] = __builtin_amdgcn_mfma_f32_16x16x32_bf16(Ah[nt], Bh, acc[nt][ct], 0, 0, 0);
          acc[nt][ct] = __builtin_amdgcn_mfma_f32_16x16x32_bf16(Al[nt], Bh, acc[nt][ct], 0, 0, 0);
          acc[nt][ct] = __builtin_amdgcn_mfma_f32_16x16x32_bf16(Ah[nt], Bl, acc[nt][ct], 0, 0, 0);
        }
      }
    }

    // ---- epilogue: s = relu(H+b1).w2; transpose so lane j<32 holds row j ----
    float myval = 0.f;
    #pragma unroll
    for (int nt = 0; nt < 2; ++nt){
      #pragma unroll
      for (int r = 0; r < 4; ++r){
        float s = 0.f;
        #pragma unroll
        for (int ct = 0; ct < 8; ++ct){
          float h = fmaxf(acc[nt][ct][r] + b1r[ct], 0.f);
          s = fmaf(h, w2r[ct], s);
        }
        s += __shfl_xor(s, 1); s += __shfl_xor(s, 2);
        s += __shfl_xor(s, 4); s += __shfl_xor(s, 8);
        const float got = __shfl(s, ((l >> 2) & 3) << 4);
        if (((l >> 4) == nt) && ((l & 3) == r)) myval = got;
      }
    }
    if (l < 32){
      const int lrow = w * 32 + l;
      const int grow = tilebase + lrow;
      const int cr = grow < NN ? grow : NN - 1;
      es[lrow]  = (grow < NN) ? __expf(myval + b2v) : 0.f;
      bsg[lrow] = is64 ? batch[2 * cr] : batch[cr];
    }
    asm volatile("s_waitcnt lgkmcnt(0)" ::: "memory");
    __builtin_amdgcn_s_barrier();
    __builtin_amdgcn_sched_barrier(0);

    // ---- pooling: 2 threads/channel, 64 rows each; x from global (L2-hot) ----
    {
      const int c = tid & 127;
      const int q = tid >> 7;
      const bool dd = (c == 0);
      float accp = 0.f, dacc = 0.f;
      int gprev = bsg[q * 64];
      for (int rr = 0; rr < 64; ++rr){
        const int r = q * 64 + rr;
        const int gg = bsg[r];
        if (gg != gprev){
          atomicAdd(&out[(size_t)gprev * CH + c], accp);
          if (dd) atomicAdd(&den[gprev], dacc);
          accp = 0.f; dacc = 0.f; gprev = gg;
        }
        int row = tilebase + r;
        row = row < NN ? row : NN - 1;
        const float e = es[r];
        accp = fmaf(e, x[(size_t)row * CH + c], accp);
        if (dd) dacc += e;
      }
      atomicAdd(&out[(size_t)gprev * CH + c], accp);
      if (dd) atomicAdd(&den[gprev], dacc);
    }
    // next phase's s_barrier separates pooling reads from future es/bs writes
  }
}

// Normalize: out[g][c] /= den[g] (0 for empty graphs)
__global__ __launch_bounds__(256) void norm_kernel(
    float* __restrict__ out, const float* __restrict__ den){
  const int idx = blockIdx.x * 256 + threadIdx.x;   // float4 index
  if (idx >= NG * 32) return;
  const int gidx = idx >> 5;
  const float d = den[gidx];
  const float inv = d > 0.f ? 1.f / d : 0.f;
  float4 v = reinterpret_cast<float4*>(out)[idx];
  v.x *= inv; v.y *= inv; v.z *= inv; v.w *= inv;
  reinterpret_cast<float4*>(out)[idx] = v;
}

extern "C" void kernel_launch(void* const* d_in, const int* in_sizes, int n_in,
                              void* d_out, int out_size, void* d_ws, size_t ws_size,
                              hipStream_t stream){
  const float* x    = (const float*)d_in[0];
  const int*   batch= (const int*)d_in[1];
  const float* W1   = (const float*)d_in[2];
  const float* b1   = (const float*)d_in[3];
  const float* w2   = (const float*)d_in[4];
  const float* b2   = (const float*)d_in[5];
  float* out = (float*)d_out;

  unsigned short* Wg = (unsigned short*)d_ws;     // 64KB pre-split W
  float* den = (float*)((char*)d_ws + 65536);     // NG floats

  prep_kernel<<<40, 256, 0, stream>>>(W1, Wg, out, den);
  fused_kernel<<<GRID, 256, 0, stream>>>(x, batch, Wg, b1, w2, b2, out, den);
  norm_kernel<<<128, 256, 0, stream>>>(out, den);
}

// Round 8
// 140.394 us; speedup vs baseline: 2.4243x; 2.4243x over previous
//
#include <hip/hip_runtime.h>
#include <math.h>

#define NN 500000
#define CH 128
#define NG 1024
#define GRID 256
#define TILES ((NN + 127) >> 7)   // 3907 tiles of 128 rows

typedef __attribute__((ext_vector_type(8))) short short8v;
typedef __attribute__((ext_vector_type(4))) float f32x4;

__device__ __forceinline__ void bf16_split(float f, unsigned short& h, unsigned short& l){
  const unsigned u = __float_as_uint(f);
  h = (unsigned short)(u >> 16);
  const float hif = __uint_as_float(u & 0xffff0000u);
  const float lof = f - hif;
  l = (unsigned short)(__float_as_uint(lof) >> 16);
}

__device__ __forceinline__ void gld_lds16(const void* g, void* l){
  __builtin_amdgcn_global_load_lds(
      (__attribute__((address_space(1))) void*)g,
      (__attribute__((address_space(3))) void*)l, 16, 0, 0);
}

// Prep: (a) t<2048: transpose + bf16-hi/lo-split W1 into Wg (pre-swizzled:
// byte = (n*256 + k*2) ^ ((n&7)<<4); hi at 0, lo at +32KB).
// (b) t in [2048, 2048+NG]: segment boundaries via lower_bound on sorted batch.
__global__ __launch_bounds__(256) void prep_kernel(
    const float* __restrict__ W1, unsigned short* __restrict__ Wg,
    const int* __restrict__ batch, int* __restrict__ start){
  const int t = blockIdx.x * 256 + threadIdx.x;
  if (t < 2048){
    const int n  = t >> 4;
    const int k0 = (t & 15) << 3;
    unsigned short hv[8], lv[8];
    #pragma unroll
    for (int i = 0; i < 8; i++)
      bf16_split(W1[(size_t)(k0 + i) * CH + n], hv[i], lv[i]);
    const int byte = (n * 256 + k0 * 2) ^ ((n & 7) << 4);
    *reinterpret_cast<short8v*>(reinterpret_cast<char*>(Wg) + byte) =
        *reinterpret_cast<short8v*>(hv);
    *reinterpret_cast<short8v*>(reinterpret_cast<char*>(Wg) + 32768 + byte) =
        *reinterpret_cast<short8v*>(lv);
  } else if (t <= 2048 + NG){
    const int g = t - 2048;
    const bool is64 = (batch[NN - 1] == 0);   // int64-vs-int32 runtime hedge
    if (g == NG){ start[NG] = NN; return; }
    int lo = 0, hi = NN;
    while (lo < hi){
      int mid = (lo + hi) >> 1;
      int v = is64 ? batch[2 * mid] : batch[mid];
      if (v < g) lo = mid + 1; else hi = mid;
    }
    start[g] = lo;
  }
}

// K1: escore[n] = exp(relu(x[n]@W1 + b1).w2 + b2). Clean T3/T4 pipeline:
// 4 x 16KB K-slice slots, prefetch depth 3, per-phase s_waitcnt vmcnt(8)
// + raw s_barrier (never drain-0 in the loop). Only stage ops (+1 store/tile)
// in the vmem queue -> counted wait retires exactly the slot being consumed.
__global__ __launch_bounds__(256, 1) void scores_mfma(
    const float* __restrict__ x, const unsigned short* __restrict__ Wg,
    const float* __restrict__ b1, const float* __restrict__ w2,
    const float* __restrict__ b2, float* __restrict__ escore)
{
  __shared__ unsigned short WB[2 * CH * CH];   // 64KB W^T hi|lo, swizzled
  __shared__ char XS[4 * 16384];               // 4 slots: 128 rows x 32 k fp32

  const int tid = threadIdx.x;
  const int w   = tid >> 6;
  const int l   = tid & 63;
  const int l15 = l & 15;
  const int g   = l >> 4;       // 0..3
  const int x7  = l15 & 7;

  const int bid = blockIdx.x;
  const int ntb = (TILES - 1 - bid) / GRID + 1;
  const int NP  = ntb * 4;
  const float b2v = b2[0];

  float b1r[8], w2r[8];
  #pragma unroll
  for (int ct = 0; ct < 8; ct++){
    b1r[ct] = b1[ct * 16 + l15];
    w2r[ct] = w2[ct * 16 + l15];
  }

  // Stage W (pre-split, coalesced, conflict-free), once.
  {
    const short8v* __restrict__ src = reinterpret_cast<const short8v*>(Wg);
    short8v* dst = reinterpret_cast<short8v*>(WB);
    #pragma unroll
    for (int it = 0; it < 16; ++it)
      dst[it * 256 + tid] = src[it * 256 + tid];
  }

  // Stage K-slice phase P (tile = bid + (P>>2)*GRID, ks = P&3) into slot P&3.
  // LDS[R][c] = src[R][c ^ (R&7)] (linear dest, pre-swizzled source).
  auto stage = [&](int P){
    char* base = XS + (P & 3) * 16384;
    const int u  = bid + (P >> 2) * GRID;
    const int ks = P & 3;
    #pragma unroll
    for (int p = 0; p < 4; ++p){
      const int idx = p * 256 + tid;     // 16B chunk id 0..1023
      const int R = idx >> 3, c = idx & 7;
      int row = u * 128 + R;
      row = row < NN ? row : NN - 1;     // clamp; stores guarded
      const char* gsrc = (const char*)x + (size_t)row * 512 + ks * 128 + ((c ^ (R & 7)) << 4);
      gld_lds16(gsrc, base + idx * 16);
    }
  };

  stage(0); stage(1); stage(2);
  __syncthreads();   // one-time drain: W + first prefetches visible

  for (int ti = 0; ti < ntb; ++ti){
    const int tilebase = (bid + ti * GRID) * 128;

    f32x4 acc[2][8];
    #pragma unroll
    for (int a = 0; a < 2; a++)
      #pragma unroll
      for (int b = 0; b < 8; b++) acc[a][b] = (f32x4)0.f;

    #pragma unroll
    for (int ks = 0; ks < 4; ++ks){
      const int P = ti * 4 + ks;
      asm volatile("s_waitcnt vmcnt(8)" ::: "memory");
      __builtin_amdgcn_s_barrier();
      __builtin_amdgcn_sched_barrier(0);
      if (P + 3 < NP) stage(P + 3);

      const char* sb = XS + ks * 16384;

      // A fragments: lane l -> x[R = w*32+nt*16+l15][k = ks*32 + g*8 + j]
      short8v Ah[2], Al[2];
      #pragma unroll
      for (int nt = 0; nt < 2; ++nt){
        const char* bp = sb + (w * 32 + nt * 16 + l15) * 128;
        float fv[8];
        *reinterpret_cast<float4*>(fv) =
            *reinterpret_cast<const float4*>(bp + (((2 * g)     ^ x7) << 4));
        *reinterpret_cast<float4*>(fv + 4) =
            *reinterpret_cast<const float4*>(bp + (((2 * g + 1) ^ x7) << 4));
        unsigned short hv[8], lv[8];
        #pragma unroll
        for (int j = 0; j < 8; j++) bf16_split(fv[j], hv[j], lv[j]);
        Ah[nt] = *reinterpret_cast<short8v*>(hv);
        Al[nt] = *reinterpret_cast<short8v*>(lv);
      }

      #pragma unroll
      for (int ct = 0; ct < 8; ++ct){
        const int n = ct * 16 + l15;
        const int byte = (n * 256 + ks * 64 + g * 16) ^ ((n & 7) << 4);
        const short8v Bh = *reinterpret_cast<const short8v*>((const char*)WB + byte);
        const short8v Bl = *reinterpret_cast<const short8v*>((const char*)WB + 32768 + byte);
        #pragma unroll
        for (int nt = 0; nt < 2; ++nt){
          acc[nt][ct] = __builtin_amdgcn_mfma_f32_16x16x32_bf16(Ah[nt], Bh, acc[nt][ct], 0, 0, 0);
          acc[nt][ct] = __builtin_amdgcn_mfma_f32_16x16x32_bf16(Al[nt], Bh, acc[nt][ct], 0, 0, 0);
          acc[nt][ct] = __builtin_amdgcn_mfma_f32_16x16x32_bf16(Ah[nt], Bl, acc[nt][ct], 0, 0, 0);
        }
      }
    }

    // Epilogue: s = relu(H+b1).w2; transpose so lane j<32 holds row j;
    // one coalesced 128B store of exp(s) per wave.
    float myval = 0.f;
    #pragma unroll
    for (int nt = 0; nt < 2; ++nt){
      #pragma unroll
      for (int r = 0; r < 4; ++r){
        float s = 0.f;
        #pragma unroll
        for (int ct = 0; ct < 8; ++ct){
          float h = fmaxf(acc[nt][ct][r] + b1r[ct], 0.f);
          s = fmaf(h, w2r[ct], s);
        }
        s += __shfl_xor(s, 1); s += __shfl_xor(s, 2);
        s += __shfl_xor(s, 4); s += __shfl_xor(s, 8);
        const float got = __shfl(s, ((l >> 2) & 3) << 4);
        if (((l >> 4) == nt) && ((l & 3) == r)) myval = got;
      }
    }
    if (l < 32){
      const int grow = tilebase + w * 32 + l;
      if (grow < NN) escore[grow] = __expf(myval + b2v);
    }
  }
}

// Pool: out[g][c] = sum_i es[i]*x[i][c] / sum_i es[i]. Single pass,
// two independent acc chains for memory-level parallelism.
__global__ __launch_bounds__(256) void pool_kernel(
    const float* __restrict__ x, const float* __restrict__ es,
    const int* __restrict__ start, float* __restrict__ out){
  const int g = blockIdx.x;
  const int s0 = start[g], s1 = start[g + 1];
  const int tid = threadIdx.x;
  const int c4 = tid & 31;   // float4 column
  const int rg = tid >> 5;   // row group 0..7

  float4 a0 = make_float4(0.f, 0.f, 0.f, 0.f);
  float4 a1 = make_float4(0.f, 0.f, 0.f, 0.f);
  float d0 = 0.f, d1 = 0.f;
  int i = s0 + rg;
  for (; i + 8 < s1; i += 16){
    const float e0 = es[i];
    const float e1 = es[i + 8];
    const float4 v0 = reinterpret_cast<const float4*>(&x[(size_t)i * CH])[c4];
    const float4 v1 = reinterpret_cast<const float4*>(&x[(size_t)(i + 8) * CH])[c4];
    a0.x = fmaf(e0, v0.x, a0.x); a0.y = fmaf(e0, v0.y, a0.y);
    a0.z = fmaf(e0, v0.z, a0.z); a0.w = fmaf(e0, v0.w, a0.w);
    d0 += e0;
    a1.x = fmaf(e1, v1.x, a1.x); a1.y = fmaf(e1, v1.y, a1.y);
    a1.z = fmaf(e1, v1.z, a1.z); a1.w = fmaf(e1, v1.w, a1.w);
    d1 += e1;
  }
  if (i < s1){
    const float e0 = es[i];
    const float4 v0 = reinterpret_cast<const float4*>(&x[(size_t)i * CH])[c4];
    a0.x = fmaf(e0, v0.x, a0.x); a0.y = fmaf(e0, v0.y, a0.y);
    a0.z = fmaf(e0, v0.z, a0.z); a0.w = fmaf(e0, v0.w, a0.w);
    d0 += e0;
  }
  a0.x += a1.x; a0.y += a1.y; a0.z += a1.z; a0.w += a1.w;
  d0 += d1;

  __shared__ float4 red[8][32];
  __shared__ float redd[8][32];
  red[rg][c4] = a0;
  redd[rg][c4] = d0;
  __syncthreads();
  if (rg < 4){
    float4 o = red[rg + 4][c4], m = red[rg][c4];
    m.x += o.x; m.y += o.y; m.z += o.z; m.w += o.w;
    red[rg][c4] = m;
    redd[rg][c4] += redd[rg + 4][c4];
  }
  __syncthreads();
  if (rg < 2){
    float4 o = red[rg + 2][c4], m = red[rg][c4];
    m.x += o.x; m.y += o.y; m.z += o.z; m.w += o.w;
    red[rg][c4] = m;
    redd[rg][c4] += redd[rg + 2][c4];
  }
  __syncthreads();
  if (rg == 0){
    float4 b0 = red[0][c4], b1v = red[1][c4];
    const float d = redd[0][c4] + redd[1][c4];
    const float inv = d > 0.f ? 1.f / d : 0.f;
    float4 r;
    r.x = (b0.x + b1v.x) * inv; r.y = (b0.y + b1v.y) * inv;
    r.z = (b0.z + b1v.z) * inv; r.w = (b0.w + b1v.w) * inv;
    reinterpret_cast<float4*>(&out[(size_t)g * CH])[c4] = r;
  }
}

extern "C" void kernel_launch(void* const* d_in, const int* in_sizes, int n_in,
                              void* d_out, int out_size, void* d_ws, size_t ws_size,
                              hipStream_t stream){
  const float* x    = (const float*)d_in[0];
  const int*   batch= (const int*)d_in[1];
  const float* W1   = (const float*)d_in[2];
  const float* b1   = (const float*)d_in[3];
  const float* w2   = (const float*)d_in[4];
  const float* b2   = (const float*)d_in[5];
  float* out = (float*)d_out;

  float* es    = (float*)d_ws;                                      // NN floats
  int*   start = (int*)((char*)d_ws + (size_t)NN * sizeof(float));  // NG+1 ints
  unsigned short* Wg = (unsigned short*)((char*)d_ws + ((ws_size - 65536) & ~(size_t)255));

  prep_kernel<<<13, 256, 0, stream>>>(W1, Wg, batch, start);
  scores_mfma<<<GRID, 256, 0, stream>>>(x, Wg, b1, w2, b2, es);
  pool_kernel<<<NG, 256, 0, stream>>>(x, es, start, out);
}